// Round 11
// baseline (1648.011 us; speedup 1.0000x reference)
//
#include <hip/hip_runtime.h>

// ---------------- types / helpers ----------------
typedef __attribute__((__ext_vector_type__(8))) __bf16 bf16x8;
typedef __attribute__((__ext_vector_type__(4))) float  f32x4;
typedef __attribute__((__ext_vector_type__(2))) float  f32x2;
typedef __attribute__((__ext_vector_type__(4))) unsigned int u32x4;
typedef unsigned short u16;
typedef unsigned int   u32;

#define DEV __device__ __forceinline__

DEV float bf2f(u16 u){ union{ float f; u32 i; } v; v.i = ((u32)u) << 16; return v.f; }
DEV u16 f2bf(float f){ union{ float f; u32 i; } v; v.f = f; u32 i = v.i;
  u32 r = i + 0x7fffu + ((i >> 16) & 1u); return (u16)(r >> 16); }
DEV float tanh_fast(float x){ float e = __expf(2.0f*x); return 1.0f - 2.0f*__builtin_amdgcn_rcpf(e + 1.0f); }
DEV float sigmoid_fast(float x){ return __builtin_amdgcn_rcpf(1.0f + __expf(-x)); }

union U8 { bf16x8 v; u16 u[8]; };

// -------- coherent (cross-XCD) access helpers: sc0 sc1 --------
DEV f32x4 ld4_sc(const float* p){ f32x4 r;
  asm volatile("global_load_dwordx4 %0, %1, off sc0 sc1" : "=v"(r) : "v"(p) : "memory"); return r; }
DEV f32x2 ld2_sc(const float* p){ f32x2 r;
  asm volatile("global_load_dwordx2 %0, %1, off sc0 sc1" : "=v"(r) : "v"(p) : "memory"); return r; }
DEV bf16x8 ldh_sc(const u16* p){ bf16x8 r;
  asm volatile("global_load_dwordx4 %0, %1, off sc0 sc1" : "=v"(r) : "v"(p) : "memory"); return r; }
DEV u32x4 ldu4_sc(const u32* p){ u32x4 r;
  asm volatile("global_load_dwordx4 %0, %1, off sc0 sc1" : "=v"(r) : "v"(p) : "memory"); return r; }
DEV u32 ldu_sc(const u32* p){ u32 r;
  asm volatile("global_load_dword %0, %1, off sc0 sc1" : "=v"(r) : "v"(p) : "memory"); return r; }
DEV void st_sc(float* p, float v){
  asm volatile("global_store_dword %0, %1, off sc0 sc1" :: "v"(p), "v"(v) : "memory"); }
DEV void stu_sc(u32* p, u32 v){
  asm volatile("global_store_dword %0, %1, off sc0 sc1" :: "v"(p), "v"(v) : "memory"); }
DEV void vwait0(){ asm volatile("s_waitcnt vmcnt(0)" ::: "memory"); __builtin_amdgcn_sched_barrier(0); }

#define B_   32
#define S_   64
#define V_   32000
#define EMB_ 512
#define D_   1024
#define G3_  3072
#define T_   63
#define NB_  256

// ---------------- workspace layout (bytes) ----------------
static const size_t OFF_FLAGS = 0;        // 256 u32 child flags; gsense at byte 2048; region 4096
static const size_t OFF_H32  = 4096;      // 32*1024*4   = 131072
static const size_t OFF_HB   = 135168;    // 32*1024*2   = 65536
static const size_t OFF_HU   = 200704;    // 32*1024*4   = 131072
static const size_t OFF_GH   = 331776;    // 32*3072*4   = 393216
static const size_t OFF_HH   = 724992;    // 2048*1024*2 = 4194304
static const size_t OFF_SCR  = 4919296;   // scratch (dead after recurrence)
static const size_t SC_M1T   = 0;          // 4096*1024*2 = 8388608
static const size_t SC_WABT  = 8388608;    // 1024*1024*2 = 2097152
static const size_t SC_ENCB  = 10485760;   // 2048*1024*2 = 4194304
static const size_t SC_EPROJ = 14680064;   // 2048*1024*2 = 4194304
static const size_t SC_WSEL  = 18874368;   // 3072*512*2  = 3145728
static const size_t SC_WCTX  = 22020096;   // 3072*1024*2 = 6291456
static const size_t SC_ENCW  = 28311552;   // 2048*3072*2 = 12582912
static const size_t SC_TEACH = 40894464;   // 2048*512*2  = 2097152
static const size_t SC_GXSEL = 42991616;   // 2048*3072*4 = 25165824 -> end 68157440

// ---------------- small kernels ----------------
__global__ void k_zero32(u32* p, int n){ int i = blockIdx.x*blockDim.x + threadIdx.x; if (i < n) p[i] = 0u; }

__global__ void k_f2b(const float* __restrict__ src, u16* __restrict__ dst, long n4){
  long i = (long)blockIdx.x*blockDim.x + threadIdx.x;
  long st = (long)gridDim.x*blockDim.x;
  for (; i < n4; i += st){
    float4 v = ((const float4*)src)[i];
    ushort4 o; o.x = f2bf(v.x); o.y = f2bf(v.y); o.z = f2bf(v.z); o.w = f2bf(v.w);
    ((ushort4*)dst)[i] = o;
  }
}

__global__ void k_transpose_f2b(const float* __restrict__ in, u16* __restrict__ out, int R, int C){
  __shared__ float tile[32][33];
  int bx = blockIdx.x, by = blockIdx.y;
  int tx = threadIdx.x & 31, ty = threadIdx.x >> 5;  // 32x8
  #pragma unroll
  for (int i = 0; i < 32; i += 8) tile[ty+i][tx] = in[(long)(by*32 + ty + i)*C + bx*32 + tx];
  __syncthreads();
  #pragma unroll
  for (int i = 0; i < 32; i += 8) out[(long)(bx*32 + ty + i)*R + by*32 + tx] = f2bf(tile[tx][ty+i]);
}

__global__ void k_subcopy(const float* __restrict__ src, u16* __restrict__ dst,
                          int rows, int srcld, int col0, int ncols){
  long total = (long)rows * (ncols >> 2);
  long i = (long)blockIdx.x*blockDim.x + threadIdx.x;
  long st = (long)gridDim.x*blockDim.x;
  int nc4 = ncols >> 2;
  for (; i < total; i += st){
    int r = (int)(i / nc4), c4 = (int)(i % nc4);
    float4 v = *(const float4*)(src + (long)r*srcld + col0 + c4*4);
    ushort4 o; o.x = f2bf(v.x); o.y = f2bf(v.y); o.z = f2bf(v.z); o.w = f2bf(v.w);
    *(ushort4*)(dst + (long)r*ncols + c4*4) = o;
  }
}

__global__ void k_teach(const float* __restrict__ emb, const int* __restrict__ tokens, u16* __restrict__ teach){
  int row = blockIdx.x;                 // t*32 + b, 0..2015
  int t = row >> 5, b = row & 31;
  int tok = tokens[b*T_ + t];
  int c = threadIdx.x * 4;              // 128 thr
  float4 v = *(const float4*)(emb + (long)tok*EMB_ + c);
  ushort4 o; o.x = f2bf(v.x); o.y = f2bf(v.y); o.z = f2bf(v.z); o.w = f2bf(v.w);
  *(ushort4*)(teach + (long)row*EMB_ + c) = o;
}

__global__ void k_h0(const float* __restrict__ h0, float* __restrict__ hf, u16* __restrict__ hb){
  int i = blockIdx.x*blockDim.x + threadIdx.x;  // 32768
  float v = h0[i]; hf[i] = v; hb[i] = f2bf(v);
}

__global__ void k_out0(float* __restrict__ out){
  int i = blockIdx.x*blockDim.x + threadIdx.x;
  if (i < B_*V_){ int b = i / V_; int v = i - b*V_;
    out[(long)b*S_*V_ + v] = (v == 0) ? 1.0f : 0.0f; }
}

// ---------------- bf16 GEMM (m97 structure): C = A[M,K] * BT[N,K]^T ----------------
// grid = (bmCount, bnCount): bm fast-varying so consecutive blocks share one B-tile.
typedef __attribute__((address_space(3))) u16 as3_u16;
typedef const __attribute__((address_space(1))) u16 as1_u16;

template<int EPI>  // 0: bf16 out, 1: f32 out + bias
__global__ __launch_bounds__(256, 2) void k_gemm(const u16* __restrict__ A, const u16* __restrict__ BT,
    float* __restrict__ outF, u16* __restrict__ outB, const float* __restrict__ bias,
    int M, int N, int K, int maskM)
{
  __shared__ u16 As[128*32], Bs[128*32];  // 8KB each, linear [128 rows][32 cols]
  const int tid = threadIdx.x, lane = tid & 63, w = tid >> 6;
  const int wm = w >> 1, wn = w & 1;
  const int bm = blockIdx.x, bn = blockIdx.y;   // bm fast -> B-tile reuse across consecutive blocks
  const u16* Ag = A + (long)bm*128*K;
  const u16* Bg = BT + (long)bn*128*K;
  const int idx0 = w*128 + lane;
  const int r0 = idx0 >> 2, kb0 = (idx0 & 3) * 8;
  const int idx1 = idx0 + 64;
  const int r1 = idx1 >> 2, kb1 = (idx1 & 3) * 8;
  f32x4 acc[4][4] = {};
  const int nkt = K >> 5;
  for (int kt = 0; kt < nkt; ++kt){
    const int k0 = kt << 5;
    __syncthreads();
    __builtin_amdgcn_global_load_lds((as1_u16*)(Ag + (long)r0*K + k0 + kb0), (as3_u16*)(As + w*1024),       16, 0, 0);
    __builtin_amdgcn_global_load_lds((as1_u16*)(Bg + (long)r0*K + k0 + kb0), (as3_u16*)(Bs + w*1024),       16, 0, 0);
    __builtin_amdgcn_global_load_lds((as1_u16*)(Ag + (long)r1*K + k0 + kb1), (as3_u16*)(As + w*1024 + 512), 16, 0, 0);
    __builtin_amdgcn_global_load_lds((as1_u16*)(Bg + (long)r1*K + k0 + kb1), (as3_u16*)(Bs + w*1024 + 512), 16, 0, 0);
    __syncthreads();
    bf16x8 af[4], bfr[4];
    #pragma unroll
    for (int i = 0; i < 4; ++i){
      int ar = wm*64 + i*16 + (lane & 15);
      af[i]  = *(const bf16x8*)(As + ar*32 + (lane >> 4)*8);
      int br = wn*64 + i*16 + (lane & 15);
      bfr[i] = *(const bf16x8*)(Bs + br*32 + (lane >> 4)*8);
    }
    #pragma unroll
    for (int i = 0; i < 4; ++i)
      #pragma unroll
      for (int j = 0; j < 4; ++j)
        acc[i][j] = __builtin_amdgcn_mfma_f32_16x16x32_bf16(af[i], bfr[j], acc[i][j], 0, 0, 0);
  }
  const int mbase = bm*128 + wm*64 + ((lane >> 4) << 2);
  const int nbase = bn*128 + wn*64 + (lane & 15);
  #pragma unroll
  for (int i = 0; i < 4; ++i){
    #pragma unroll
    for (int j = 0; j < 4; ++j){
      int n = nbase + j*16;
      #pragma unroll
      for (int q = 0; q < 4; ++q){
        int m = mbase + i*16 + q;
        float v = acc[i][j][q];
        if constexpr (EPI == 0){
          outB[(long)m*N + n] = f2bf(v);
        } else {
          outF[(long)m*N + n] = v + bias[n];
        }
      }
    }
  }
}

// ---- logits GEMM with fused f32->bf16 B-staging: C = A[M,K](bf16) * Bf[N,K](f32)^T ----
// B tile reg-staged: thread (r=tid>>1, hf=tid&1) loads 16 f32 of row r, converts (RNE,
// identical to k_f2b), writes 32B to Bs[r*32 + hf*16]. A staged via global_load_lds.
// Epilogue: out[b][t+1][n] remap + bias, masked to m < maskM.
__global__ __launch_bounds__(256, 2) void k_gemmF(const u16* __restrict__ A, const float* __restrict__ Bf,
    float* __restrict__ outF, const float* __restrict__ bias, int M, int N, int K, int maskM)
{
  __shared__ u16 As[128*32], Bs[128*32];
  const int tid = threadIdx.x, lane = tid & 63, w = tid >> 6;
  const int wm = w >> 1, wn = w & 1;
  const int bm = blockIdx.x, bn = blockIdx.y;   // bm fast -> B-tile (W_out) swept ~once
  const u16* Ag = A + (long)bm*128*K;
  const float* Bg = Bf + (long)(bn*128)*K;
  const int idx0 = w*128 + lane;
  const int r0 = idx0 >> 2, kb0 = (idx0 & 3) * 8;
  const int idx1 = idx0 + 64;
  const int r1 = idx1 >> 2, kb1 = (idx1 & 3) * 8;
  const int br_ = tid >> 1, bhf = tid & 1;      // B-staging ids: row, 16-col half
  f32x4 acc[4][4] = {};
  const int nkt = K >> 5;
  for (int kt = 0; kt < nkt; ++kt){
    const int k0 = kt << 5;
    __syncthreads();
    __builtin_amdgcn_global_load_lds((as1_u16*)(Ag + (long)r0*K + k0 + kb0), (as3_u16*)(As + w*1024),       16, 0, 0);
    __builtin_amdgcn_global_load_lds((as1_u16*)(Ag + (long)r1*K + k0 + kb1), (as3_u16*)(As + w*1024 + 512), 16, 0, 0);
    {
      const float* bp = Bg + (long)br_*K + k0 + bhf*16;
      float4 v0 = *(const float4*)(bp);
      float4 v1 = *(const float4*)(bp + 4);
      float4 v2 = *(const float4*)(bp + 8);
      float4 v3 = *(const float4*)(bp + 12);
      u16* dst = Bs + br_*32 + bhf*16;
      ushort4 o0, o1, o2, o3;
      o0.x = f2bf(v0.x); o0.y = f2bf(v0.y); o0.z = f2bf(v0.z); o0.w = f2bf(v0.w);
      o1.x = f2bf(v1.x); o1.y = f2bf(v1.y); o1.z = f2bf(v1.z); o1.w = f2bf(v1.w);
      o2.x = f2bf(v2.x); o2.y = f2bf(v2.y); o2.z = f2bf(v2.z); o2.w = f2bf(v2.w);
      o3.x = f2bf(v3.x); o3.y = f2bf(v3.y); o3.z = f2bf(v3.z); o3.w = f2bf(v3.w);
      *(ushort4*)(dst)      = o0;
      *(ushort4*)(dst + 4)  = o1;
      *(ushort4*)(dst + 8)  = o2;
      *(ushort4*)(dst + 12) = o3;
    }
    __syncthreads();
    bf16x8 af[4], bfr[4];
    #pragma unroll
    for (int i = 0; i < 4; ++i){
      int ar = wm*64 + i*16 + (lane & 15);
      af[i]  = *(const bf16x8*)(As + ar*32 + (lane >> 4)*8);
      int br = wn*64 + i*16 + (lane & 15);
      bfr[i] = *(const bf16x8*)(Bs + br*32 + (lane >> 4)*8);
    }
    #pragma unroll
    for (int i = 0; i < 4; ++i)
      #pragma unroll
      for (int j = 0; j < 4; ++j)
        acc[i][j] = __builtin_amdgcn_mfma_f32_16x16x32_bf16(af[i], bfr[j], acc[i][j], 0, 0, 0);
  }
  const int mbase = bm*128 + wm*64 + ((lane >> 4) << 2);
  const int nbase = bn*128 + wn*64 + (lane & 15);
  #pragma unroll
  for (int i = 0; i < 4; ++i){
    #pragma unroll
    for (int j = 0; j < 4; ++j){
      int n = nbase + j*16;
      #pragma unroll
      for (int q = 0; q < 4; ++q){
        int m = mbase + i*16 + q;
        if (m < maskM){
          int b = m & 31, t = m >> 5;
          outF[((long)b*S_ + t + 1)*V_ + n] = acc[i][j][q] + bias[n];
        }
      }
    }
  }
}

// ---------------- grid barrier: gsense pre-gate + r3-proven release condition ----------------
// (byte-identical to round 7/9, which passed)
DEV void grid_barrier(u32* flags, u32* gsense, u32 ep, int tid, int blk){
  asm volatile("s_waitcnt vmcnt(0)" ::: "memory");   // drain own coherent stores
  __syncthreads();
  if (tid == 0) stu_sc(flags + blk, ep);
  if (blk != 0 && tid < 64){
    int spins = 0;
    while (true){
      u32 g = ldu_sc(gsense);
      asm volatile("s_waitcnt vmcnt(0)" ::: "memory");
      if (g >= ep) break;
      if (++spins > (1 << 20)) break;  // fail visibly, never hang
      __builtin_amdgcn_s_sleep(4);
    }
  }
  if (tid < 64){
    const u32* fp = flags + tid*4;
    int spins = 0;
    while (true){
      u32x4 f = ldu4_sc(fp);
      asm volatile("s_waitcnt vmcnt(0)" ::: "memory");
      u32 mn = f[0] < f[1] ? f[0] : f[1];
      u32 m2 = f[2] < f[3] ? f[2] : f[3];
      mn = mn < m2 ? mn : m2;
      #pragma unroll
      for (int off = 32; off; off >>= 1){
        u32 o = (u32)__shfl_xor((int)mn, off);
        mn = mn < o ? mn : o;
      }
      if (mn >= ep) break;
      if (++spins > (1 << 20)) break;  // fail visibly, never hang
      __builtin_amdgcn_s_sleep(2);
    }
    if (blk == 0 && tid == 0) stu_sc(gsense, ep);   // publish after full observation
  }
  __syncthreads();
}

// ---------------- persistent recurrence kernel (round-9, byte-identical; PASSED; FROZEN) ----
// 256 blocks x 512 threads, 2 barriers/step.
// Phase A : [hU|gh] cols split 16/block; waves = 2 m-tiles x 4 k-splits; LDS k-reduce.
// Phase BC: 8 blocks per b (blk&31==b): dup scores+softmax; ctx slice 128 dims, s-loop
//           8-way wave-split + LDS reduce; gates on wave 0 with prefetched inputs.
__global__ __launch_bounds__(512, 2) void k_recur(
    float* __restrict__ h_f32, u16* __restrict__ h_b16,
    float* __restrict__ hU, float* __restrict__ gh,
    u16* __restrict__ H,
    const u16* __restrict__ M1T, const u16* __restrict__ enc_proj,
    const u16* __restrict__ encW, const float* __restrict__ gx_sel,
    const float* __restrict__ v_a, const float* __restrict__ b_hh,
    const int* __restrict__ lengths, u32* __restrict__ flags, u32* __restrict__ gsense)
{
  const int blk = blockIdx.x;   // 256
  const int tid = threadIdx.x;  // 512
  const int lane = tid & 63, w = tid >> 6;    // 8 waves
  __shared__ float __attribute__((aligned(16))) shred[8*64*7];  // 14KB, multi-use
  __shared__ float sc_lds[64], wls[64];

  // Phase A ids
  const int wk = w >> 1, mt = w & 1;
  const int c0 = blk * 16;
  const int acol = c0 + (lane & 15);
  const u16* Bb = M1T + (long)acol * D_;
  const int arow = mt*16 + (lane & 15);
  // Phase BC ids
  const int bB = blk & 31, slice = blk >> 5;   // 8 slice-blocks per b, same XCD (blk%8==bB%8)
  const int len = lengths[bB];
  const int d0 = lane * 16;
  const int dt = tid & 63;
  const int d2c = slice*128 + dt*2;            // ctx/gates dim pair

  float va[16];
  #pragma unroll
  for (int q = 0; q < 4; ++q){
    float4 t4 = *(const float4*)(v_a + d0 + q*4);
    va[q*4+0] = t4.x; va[q*4+1] = t4.y; va[q*4+2] = t4.z; va[q*4+3] = t4.w;
  }
  u32 ep = 0;

  for (int t = 0; t < T_; ++t){
    // ===== Phase A: [hU|gh] cols [c0, c0+16) =====
    {
      bf16x8 af[8], bfr[8];
      #pragma unroll
      for (int i = 0; i < 8; ++i){
        int kk = wk*256 + i*32 + ((lane >> 4) << 3);
        af[i]  = ldh_sc(h_b16 + arow*D_ + kk);
        bfr[i] = *(const bf16x8*)(Bb + kk);
      }
      vwait0();
      f32x4 acc = {0.f, 0.f, 0.f, 0.f};
      #pragma unroll
      for (int i = 0; i < 8; ++i)
        acc = __builtin_amdgcn_mfma_f32_16x16x32_bf16(af[i], bfr[i], acc, 0, 0, 0);
      *(f32x4*)(shred + (w*64 + lane)*4) = acc;
    }
    __syncthreads();
    {
      int mt2 = tid >> 8, lq = tid & 255, lane2 = lq >> 2, q = lq & 3;
      float s = 0.f;
      #pragma unroll
      for (int wk2 = 0; wk2 < 4; ++wk2) s += shred[((wk2*2 + mt2)*64 + lane2)*4 + q];
      int m = mt2*16 + ((lane2 >> 4) << 2) + q;
      int nc = c0 + (lane2 & 15);
      if (nc < D_) st_sc(hU + m*D_ + nc, s);
      else         st_sc(gh + m*G3_ + (nc - D_), s + b_hh[nc - D_]);
    }
    grid_barrier(flags, gsense, ++ep, tid, blk);

    // ===== Phase BC =====
    // prefetch gate inputs (wave 0 only) — latency hides under scores
    f32x2 g0, g1, g2; float2 gsr, gsz, gsn, hv;
    if (tid < 64){
      const float* ghp = gh + bB*G3_;
      g0 = ld2_sc(ghp + d2c); g1 = ld2_sc(ghp + D_ + d2c); g2 = ld2_sc(ghp + 2*D_ + d2c);
      const float* gs = gx_sel + ((long)t*B_ + bB)*G3_;
      gsr = *(const float2*)(gs + d2c);
      gsz = *(const float2*)(gs + D_ + d2c);
      gsn = *(const float2*)(gs + 2*D_ + d2c);
      hv  = *(const float2*)(h_f32 + bB*D_ + d2c);
    }
    // hu: full hU[bB] row, 16 dims/lane (dup across waves)
    float hu[16];
    {
      const float* hup = hU + bB*D_ + d0;
      f32x4 a0 = ld4_sc(hup), a1 = ld4_sc(hup+4), a2 = ld4_sc(hup+8), a3 = ld4_sc(hup+12);
      vwait0();
      #pragma unroll
      for (int q = 0; q < 4; ++q){ hu[q] = a0[q]; hu[4+q] = a1[q]; hu[8+q] = a2[q]; hu[12+q] = a3[q]; }
    }
    // scores for all s (dup x8 blocks): wave w -> s = w*8..w*8+7
    #pragma unroll
    for (int i = 0; i < 8; ++i){
      int s = w*8 + i;
      if (s < len){
        const u16* epp = enc_proj + ((long)(bB*S_ + s))*D_ + d0;
        U8 e0, e1; e0.v = *(const bf16x8*)epp; e1.v = *(const bf16x8*)(epp + 8);
        float a = 0.f;
        #pragma unroll
        for (int e = 0; e < 8; ++e){
          a = fmaf(tanh_fast(bf2f(e0.u[e]) + hu[e]),     va[e],     a);
          a = fmaf(tanh_fast(bf2f(e1.u[e]) + hu[8 + e]), va[8 + e], a);
        }
        #pragma unroll
        for (int off = 32; off; off >>= 1) a += __shfl_xor(a, off);
        if (lane == 0) sc_lds[s] = a;
      }
    }
    __syncthreads();
    if (w == 0){
      int s = lane;
      float x = (s < len) ? sc_lds[s] : -1e30f;
      float m = x;
      #pragma unroll
      for (int off = 32; off; off >>= 1) m = fmaxf(m, __shfl_xor(m, off));
      float e = (s < len) ? __expf(x - m) : 0.f;
      float sum = e;
      #pragma unroll
      for (int off = 32; off; off >>= 1) sum += __shfl_xor(sum, off);
      wls[s] = e * __builtin_amdgcn_rcpf(sum);
    }
    __syncthreads();
    // ctx: thread (sgrp=w, dt): dims (d2c, d2c+1) of each gate; s-loop 8-way split
    {
      float ar0=0,ar1=0,az0=0,az1=0,an0=0,an1=0;
      const u16* basep = encW + (long)bB*S_*G3_ + d2c;
      #pragma unroll
      for (int j = 0; j < 8; ++j){
        int s = w + j*8;
        if (s < len){
          const u16* p = basep + (long)s*G3_;
          u32 rr = *(const u32*)p;
          u32 zz = *(const u32*)(p + D_);
          u32 nn = *(const u32*)(p + 2*D_);
          float wt = wls[s];
          ar0 = fmaf(wt, bf2f((u16)rr), ar0);  ar1 = fmaf(wt, bf2f((u16)(rr >> 16)), ar1);
          az0 = fmaf(wt, bf2f((u16)zz), az0);  az1 = fmaf(wt, bf2f((u16)(zz >> 16)), az1);
          an0 = fmaf(wt, bf2f((u16)nn), an0);  an1 = fmaf(wt, bf2f((u16)(nn >> 16)), an1);
        }
      }
      float* pp = shred + (w*64 + dt)*7;
      pp[0]=ar0; pp[1]=ar1; pp[2]=az0; pp[3]=az1; pp[4]=an0; pp[5]=an1;
    }
    __syncthreads();
    if (tid < 64){
      float ar0=0,ar1=0,az0=0,az1=0,an0=0,an1=0;
      #pragma unroll
      for (int g = 0; g < 8; ++g){
        const float* pp = shred + (g*64 + tid)*7;
        ar0 += pp[0]; ar1 += pp[1]; az0 += pp[2]; az1 += pp[3]; an0 += pp[4]; an1 += pp[5];
      }
      float r0 = sigmoid_fast(gsr.x + ar0 + g0[0]);
      float r1 = sigmoid_fast(gsr.y + ar1 + g0[1]);
      float z0 = sigmoid_fast(gsz.x + az0 + g1[0]);
      float z1 = sigmoid_fast(gsz.y + az1 + g1[1]);
      float n0 = tanh_fast(gsn.x + an0 + r0*g2[0]);
      float n1 = tanh_fast(gsn.y + an1 + r1*g2[1]);
      float hn0 = (1.f - z0)*n0 + z0*hv.x;
      float hn1 = (1.f - z1)*n1 + z1*hv.y;
      *(float2*)(h_f32 + bB*D_ + d2c) = make_float2(hn0, hn1);   // block-private
      u32 pack = ((u32)f2bf(hn1) << 16) | (u32)f2bf(hn0);
      stu_sc((u32*)(h_b16 + bB*D_ + d2c), pack);                 // coherent: read by all blocks
      long row = (long)t*B_ + bB;
      *(u32*)(H + row*D_ + d2c) = pack;                          // read after kernel end
    }
    grid_barrier(flags, gsense, ++ep, tid, blk);
  }
}

// ---------------- launch ----------------
extern "C" void kernel_launch(void* const* d_in, const int* in_sizes, int n_in,
                              void* d_out, int out_size, void* d_ws, size_t ws_size,
                              hipStream_t stream)
{
  const int*   tokens    = (const int*)  d_in[0];
  const float* hidden0   = (const float*)d_in[1];
  const float* enc       = (const float*)d_in[2];
  const int*   lengths   = (const int*)  d_in[3];
  // d_in[4] = teacher_forcing_ratio (1.0 -> teacher forcing always; greedy path dead)
  const float* embedding = (const float*)d_in[5];
  const float* Wa        = (const float*)d_in[6];
  const float* Ua        = (const float*)d_in[7];
  const float* v_a       = (const float*)d_in[8];
  const float* W_ih      = (const float*)d_in[9];
  const float* b_ih      = (const float*)d_in[10];
  const float* W_hh      = (const float*)d_in[11];
  const float* b_hh      = (const float*)d_in[12];
  const float* W_out     = (const float*)d_in[13];
  const float* b_out     = (const float*)d_in[14];
  float* out = (float*)d_out;
  char* ws = (char*)d_ws;

  u32*   flags    = (u32*)  (ws + OFF_FLAGS);
  u32*   gsense   = (u32*)  (ws + OFF_FLAGS + 2048);
  float* h_f32    = (float*)(ws + OFF_H32);
  u16*   h_b16    = (u16*)  (ws + OFF_HB);
  float* hU       = (float*)(ws + OFF_HU);
  float* gh       = (float*)(ws + OFF_GH);
  u16*   H        = (u16*)  (ws + OFF_HH);
  char*  scr      = ws + OFF_SCR;
  u16*   M1T      = (u16*)  (scr + SC_M1T);
  u16*   Wa_bt    = (u16*)  (scr + SC_WABT);
  u16*   enc_b    = (u16*)  (scr + SC_ENCB);
  u16*   eproj    = (u16*)  (scr + SC_EPROJ);
  u16*   Wsel     = (u16*)  (scr + SC_WSEL);
  u16*   Wctx     = (u16*)  (scr + SC_WCTX);
  u16*   encW     = (u16*)  (scr + SC_ENCW);
  u16*   teach    = (u16*)  (scr + SC_TEACH);
  float* gx_sel   = (float*)(scr + SC_GXSEL);

  // init + weight conversion / precompute
  k_zero32<<<dim3(4), dim3(256), 0, stream>>>((u32*)(ws + OFF_FLAGS), 1024);  // flags + gsense region
  k_f2b<<<dim3(2048), dim3(256), 0, stream>>>(enc, enc_b, (long)(2048*1024/4));
  k_transpose_f2b<<<dim3(32,32), dim3(256), 0, stream>>>(Ua, M1T, 1024, 1024);       // M1T[n][k]=Ua[k][n]
  k_transpose_f2b<<<dim3(32,32), dim3(256), 0, stream>>>(Wa, Wa_bt, 1024, 1024);     // Wa_bt[d][e]=Wa[e][d]
  k_f2b<<<dim3(2048), dim3(256), 0, stream>>>(W_hh, M1T + 1024*1024, (long)(3072*1024/4));
  k_subcopy<<<dim3(2048), dim3(256), 0, stream>>>(W_ih, Wsel, 3072, 1536, 0, 512);
  k_subcopy<<<dim3(2048), dim3(256), 0, stream>>>(W_ih, Wctx, 3072, 1536, 512, 1024);
  k_teach<<<dim3(2016), dim3(128), 0, stream>>>(embedding, tokens, teach);
  k_h0<<<dim3(128), dim3(256), 0, stream>>>(hidden0, h_f32, h_b16);

  // precompute GEMMs (grid = (bm, bn): bm fast for B-tile L2/HBM reuse)
  k_gemm<0><<<dim3(16,8),  dim3(256), 0, stream>>>(enc_b, Wa_bt, nullptr, eproj, nullptr, 2048, 1024, 1024, 2048);
  k_gemm<0><<<dim3(16,24), dim3(256), 0, stream>>>(enc_b, Wctx,  nullptr, encW,  nullptr, 2048, 3072, 1024, 2048);
  k_gemm<1><<<dim3(16,24), dim3(256), 0, stream>>>(teach, Wsel,  gx_sel, nullptr, b_ih,  2048, 3072, 512,  2048);

  // 63-step recurrence (persistent, 256 co-resident blocks, r7 barriers — byte-identical)
  k_recur<<<dim3(NB_), dim3(512), 0, stream>>>(h_f32, h_b16, hU, gh, H,
                                               M1T, eproj, encW, gx_sel, v_a, b_hh, lengths,
                                               flags, gsense);

  // batched output projection: fused f32->bf16 B staging (no separate W_out conversion pass)
  k_gemmF<<<dim3(16,250), dim3(256), 0, stream>>>(H, W_out, out, b_out, 2048, 32000, 1024, 2016);
  k_out0<<<dim3(1000), dim3(1024), 0, stream>>>(out);
}

// Round 12
// 1544.930 us; speedup vs baseline: 1.0667x; 1.0667x over previous
//
#include <hip/hip_runtime.h>

// ---------------- types / helpers ----------------
typedef __attribute__((__ext_vector_type__(8))) __bf16 bf16x8;
typedef __attribute__((__ext_vector_type__(4))) float  f32x4;
typedef __attribute__((__ext_vector_type__(2))) float  f32x2;
typedef __attribute__((__ext_vector_type__(4))) unsigned int u32x4;
typedef unsigned short u16;
typedef unsigned int   u32;

#define DEV __device__ __forceinline__

DEV float bf2f(u16 u){ union{ float f; u32 i; } v; v.i = ((u32)u) << 16; return v.f; }
DEV u16 f2bf(float f){ union{ float f; u32 i; } v; v.f = f; u32 i = v.i;
  u32 r = i + 0x7fffu + ((i >> 16) & 1u); return (u16)(r >> 16); }
DEV float tanh_fast(float x){ float e = __expf(2.0f*x); return 1.0f - 2.0f*__builtin_amdgcn_rcpf(e + 1.0f); }
DEV float sigmoid_fast(float x){ return __builtin_amdgcn_rcpf(1.0f + __expf(-x)); }

union U8 { bf16x8 v; u16 u[8]; };

// -------- coherent (cross-XCD) access helpers: sc0 sc1 --------
DEV f32x4 ld4_sc(const float* p){ f32x4 r;
  asm volatile("global_load_dwordx4 %0, %1, off sc0 sc1" : "=v"(r) : "v"(p) : "memory"); return r; }
DEV f32x2 ld2_sc(const float* p){ f32x2 r;
  asm volatile("global_load_dwordx2 %0, %1, off sc0 sc1" : "=v"(r) : "v"(p) : "memory"); return r; }
DEV bf16x8 ldh_sc(const u16* p){ bf16x8 r;
  asm volatile("global_load_dwordx4 %0, %1, off sc0 sc1" : "=v"(r) : "v"(p) : "memory"); return r; }
DEV u32x4 ldu4_sc(const u32* p){ u32x4 r;
  asm volatile("global_load_dwordx4 %0, %1, off sc0 sc1" : "=v"(r) : "v"(p) : "memory"); return r; }
DEV u32 ldu_sc(const u32* p){ u32 r;
  asm volatile("global_load_dword %0, %1, off sc0 sc1" : "=v"(r) : "v"(p) : "memory"); return r; }
DEV void st_sc(float* p, float v){
  asm volatile("global_store_dword %0, %1, off sc0 sc1" :: "v"(p), "v"(v) : "memory"); }
DEV void stu_sc(u32* p, u32 v){
  asm volatile("global_store_dword %0, %1, off sc0 sc1" :: "v"(p), "v"(v) : "memory"); }
DEV void vwait0(){ asm volatile("s_waitcnt vmcnt(0)" ::: "memory"); __builtin_amdgcn_sched_barrier(0); }

#define B_   32
#define S_   64
#define V_   32000
#define EMB_ 512
#define D_   1024
#define G3_  3072
#define T_   63
#define NB_  256

// ---------------- workspace layout (bytes) ----------------
static const size_t OFF_FLAGS = 0;        // 256 u32 child flags; gsense at byte 2048; region 4096
static const size_t OFF_H32  = 4096;      // 32*1024*4   = 131072
static const size_t OFF_HB   = 135168;    // 32*1024*2   = 65536
static const size_t OFF_HU   = 200704;    // 32*1024*4   = 131072
static const size_t OFF_GH   = 331776;    // 32*3072*4   = 393216
static const size_t OFF_HH   = 724992;    // 2048*1024*2 = 4194304
static const size_t OFF_SCR  = 4919296;   // scratch (dead after recurrence)
static const size_t SC_M1T   = 0;          // 4096*1024*2 = 8388608
static const size_t SC_WABT  = 8388608;    // 1024*1024*2 = 2097152
static const size_t SC_ENCB  = 10485760;   // 2048*1024*2 = 4194304
static const size_t SC_EPROJ = 14680064;   // 2048*1024*2 = 4194304
static const size_t SC_WSEL  = 18874368;   // 3072*512*2  = 3145728
static const size_t SC_WCTX  = 22020096;   // 3072*1024*2 = 6291456
static const size_t SC_ENCW  = 28311552;   // 2048*3072*2 = 12582912
static const size_t SC_TEACH = 40894464;   // 2048*512*2  = 2097152
static const size_t SC_GXSEL = 42991616;   // 2048*3072*4 = 25165824 -> end 68157440
// W_out bf16 overlays scratch base after recurrence (65,536,000 <= 68,157,440)

// ---------------- small kernels ----------------
__global__ void k_zero32(u32* p, int n){ int i = blockIdx.x*blockDim.x + threadIdx.x; if (i < n) p[i] = 0u; }

__global__ void k_f2b(const float* __restrict__ src, u16* __restrict__ dst, long n4){
  long i = (long)blockIdx.x*blockDim.x + threadIdx.x;
  long st = (long)gridDim.x*blockDim.x;
  for (; i < n4; i += st){
    float4 v = ((const float4*)src)[i];
    ushort4 o; o.x = f2bf(v.x); o.y = f2bf(v.y); o.z = f2bf(v.z); o.w = f2bf(v.w);
    ((ushort4*)dst)[i] = o;
  }
}

__global__ void k_transpose_f2b(const float* __restrict__ in, u16* __restrict__ out, int R, int C){
  __shared__ float tile[32][33];
  int bx = blockIdx.x, by = blockIdx.y;
  int tx = threadIdx.x & 31, ty = threadIdx.x >> 5;  // 32x8
  #pragma unroll
  for (int i = 0; i < 32; i += 8) tile[ty+i][tx] = in[(long)(by*32 + ty + i)*C + bx*32 + tx];
  __syncthreads();
  #pragma unroll
  for (int i = 0; i < 32; i += 8) out[(long)(bx*32 + ty + i)*R + by*32 + tx] = f2bf(tile[tx][ty+i]);
}

__global__ void k_subcopy(const float* __restrict__ src, u16* __restrict__ dst,
                          int rows, int srcld, int col0, int ncols){
  long total = (long)rows * (ncols >> 2);
  long i = (long)blockIdx.x*blockDim.x + threadIdx.x;
  long st = (long)gridDim.x*blockDim.x;
  int nc4 = ncols >> 2;
  for (; i < total; i += st){
    int r = (int)(i / nc4), c4 = (int)(i % nc4);
    float4 v = *(const float4*)(src + (long)r*srcld + col0 + c4*4);
    ushort4 o; o.x = f2bf(v.x); o.y = f2bf(v.y); o.z = f2bf(v.z); o.w = f2bf(v.w);
    *(ushort4*)(dst + (long)r*ncols + c4*4) = o;
  }
}

__global__ void k_teach(const float* __restrict__ emb, const int* __restrict__ tokens, u16* __restrict__ teach){
  int row = blockIdx.x;                 // t*32 + b, 0..2015
  int t = row >> 5, b = row & 31;
  int tok = tokens[b*T_ + t];
  int c = threadIdx.x * 4;              // 128 thr
  float4 v = *(const float4*)(emb + (long)tok*EMB_ + c);
  ushort4 o; o.x = f2bf(v.x); o.y = f2bf(v.y); o.z = f2bf(v.z); o.w = f2bf(v.w);
  *(ushort4*)(teach + (long)row*EMB_ + c) = o;
}

__global__ void k_h0(const float* __restrict__ h0, float* __restrict__ hf, u16* __restrict__ hb){
  int i = blockIdx.x*blockDim.x + threadIdx.x;  // 32768
  float v = h0[i]; hf[i] = v; hb[i] = f2bf(v);
}

__global__ void k_out0(float* __restrict__ out){
  int i = blockIdx.x*blockDim.x + threadIdx.x;
  if (i < B_*V_){ int b = i / V_; int v = i - b*V_;
    out[(long)b*S_*V_ + v] = (v == 0) ? 1.0f : 0.0f; }
}

// ---------------- bf16 GEMM (m97 structure): C = A[M,K] * BT[N,K]^T ----------------
// grid = (bmCount, bnCount): bm fast-varying so consecutive blocks share one B-tile.
typedef __attribute__((address_space(3))) u16 as3_u16;
typedef const __attribute__((address_space(1))) u16 as1_u16;

template<int EPI>  // 0: bf16 out, 1: f32 out + bias, 2: logits -> d_out remap + bias, masked
__global__ __launch_bounds__(256, 2) void k_gemm(const u16* __restrict__ A, const u16* __restrict__ BT,
    float* __restrict__ outF, u16* __restrict__ outB, const float* __restrict__ bias,
    int M, int N, int K, int maskM)
{
  __shared__ u16 As[128*32], Bs[128*32];  // 8KB each, linear [128 rows][32 cols]
  const int tid = threadIdx.x, lane = tid & 63, w = tid >> 6;
  const int wm = w >> 1, wn = w & 1;
  const int bm = blockIdx.x, bn = blockIdx.y;   // bm fast -> B-tile reuse across consecutive blocks
  const u16* Ag = A + (long)bm*128*K;
  const u16* Bg = BT + (long)bn*128*K;
  const int idx0 = w*128 + lane;
  const int r0 = idx0 >> 2, kb0 = (idx0 & 3) * 8;
  const int idx1 = idx0 + 64;
  const int r1 = idx1 >> 2, kb1 = (idx1 & 3) * 8;
  f32x4 acc[4][4] = {};
  const int nkt = K >> 5;
  for (int kt = 0; kt < nkt; ++kt){
    const int k0 = kt << 5;
    __syncthreads();
    __builtin_amdgcn_global_load_lds((as1_u16*)(Ag + (long)r0*K + k0 + kb0), (as3_u16*)(As + w*1024),       16, 0, 0);
    __builtin_amdgcn_global_load_lds((as1_u16*)(Bg + (long)r0*K + k0 + kb0), (as3_u16*)(Bs + w*1024),       16, 0, 0);
    __builtin_amdgcn_global_load_lds((as1_u16*)(Ag + (long)r1*K + k0 + kb1), (as3_u16*)(As + w*1024 + 512), 16, 0, 0);
    __builtin_amdgcn_global_load_lds((as1_u16*)(Bg + (long)r1*K + k0 + kb1), (as3_u16*)(Bs + w*1024 + 512), 16, 0, 0);
    __syncthreads();
    bf16x8 af[4], bfr[4];
    #pragma unroll
    for (int i = 0; i < 4; ++i){
      int ar = wm*64 + i*16 + (lane & 15);
      af[i]  = *(const bf16x8*)(As + ar*32 + (lane >> 4)*8);
      int br = wn*64 + i*16 + (lane & 15);
      bfr[i] = *(const bf16x8*)(Bs + br*32 + (lane >> 4)*8);
    }
    #pragma unroll
    for (int i = 0; i < 4; ++i)
      #pragma unroll
      for (int j = 0; j < 4; ++j)
        acc[i][j] = __builtin_amdgcn_mfma_f32_16x16x32_bf16(af[i], bfr[j], acc[i][j], 0, 0, 0);
  }
  const int mbase = bm*128 + wm*64 + ((lane >> 4) << 2);
  const int nbase = bn*128 + wn*64 + (lane & 15);
  #pragma unroll
  for (int i = 0; i < 4; ++i){
    #pragma unroll
    for (int j = 0; j < 4; ++j){
      int n = nbase + j*16;
      #pragma unroll
      for (int q = 0; q < 4; ++q){
        int m = mbase + i*16 + q;
        float v = acc[i][j][q];
        if constexpr (EPI == 0){
          outB[(long)m*N + n] = f2bf(v);
        } else if constexpr (EPI == 1){
          outF[(long)m*N + n] = v + bias[n];
        } else {
          if (m < maskM){
            int b = m & 31, t = m >> 5;
            outF[((long)b*S_ + t + 1)*V_ + n] = v + bias[n];
          }
        }
      }
    }
  }
}

// ---------------- grid barrier: gsense pre-gate + r3-proven release condition ----------------
// (byte-identical to round 7/9, which passed)
DEV void grid_barrier(u32* flags, u32* gsense, u32 ep, int tid, int blk){
  asm volatile("s_waitcnt vmcnt(0)" ::: "memory");   // drain own coherent stores
  __syncthreads();
  if (tid == 0) stu_sc(flags + blk, ep);
  if (blk != 0 && tid < 64){
    int spins = 0;
    while (true){
      u32 g = ldu_sc(gsense);
      asm volatile("s_waitcnt vmcnt(0)" ::: "memory");
      if (g >= ep) break;
      if (++spins > (1 << 20)) break;  // fail visibly, never hang
      __builtin_amdgcn_s_sleep(4);
    }
  }
  if (tid < 64){
    const u32* fp = flags + tid*4;
    int spins = 0;
    while (true){
      u32x4 f = ldu4_sc(fp);
      asm volatile("s_waitcnt vmcnt(0)" ::: "memory");
      u32 mn = f[0] < f[1] ? f[0] : f[1];
      u32 m2 = f[2] < f[3] ? f[2] : f[3];
      mn = mn < m2 ? mn : m2;
      #pragma unroll
      for (int off = 32; off; off >>= 1){
        u32 o = (u32)__shfl_xor((int)mn, off);
        mn = mn < o ? mn : o;
      }
      if (mn >= ep) break;
      if (++spins > (1 << 20)) break;  // fail visibly, never hang
      __builtin_amdgcn_s_sleep(2);
    }
    if (blk == 0 && tid == 0) stu_sc(gsense, ep);   // publish after full observation
  }
  __syncthreads();
}

// ---------------- persistent recurrence kernel (round-9, byte-identical; PASSED; FROZEN) ----
// 256 blocks x 512 threads, 2 barriers/step.
// Phase A : [hU|gh] cols split 16/block; waves = 2 m-tiles x 4 k-splits; LDS k-reduce.
// Phase BC: 8 blocks per b (blk&31==b): dup scores+softmax; ctx slice 128 dims, s-loop
//           8-way wave-split + LDS reduce; gates on wave 0 with prefetched inputs.
__global__ __launch_bounds__(512, 2) void k_recur(
    float* __restrict__ h_f32, u16* __restrict__ h_b16,
    float* __restrict__ hU, float* __restrict__ gh,
    u16* __restrict__ H,
    const u16* __restrict__ M1T, const u16* __restrict__ enc_proj,
    const u16* __restrict__ encW, const float* __restrict__ gx_sel,
    const float* __restrict__ v_a, const float* __restrict__ b_hh,
    const int* __restrict__ lengths, u32* __restrict__ flags, u32* __restrict__ gsense)
{
  const int blk = blockIdx.x;   // 256
  const int tid = threadIdx.x;  // 512
  const int lane = tid & 63, w = tid >> 6;    // 8 waves
  __shared__ float __attribute__((aligned(16))) shred[8*64*7];  // 14KB, multi-use
  __shared__ float sc_lds[64], wls[64];

  // Phase A ids
  const int wk = w >> 1, mt = w & 1;
  const int c0 = blk * 16;
  const int acol = c0 + (lane & 15);
  const u16* Bb = M1T + (long)acol * D_;
  const int arow = mt*16 + (lane & 15);
  // Phase BC ids
  const int bB = blk & 31, slice = blk >> 5;   // 8 slice-blocks per b, same XCD (blk%8==bB%8)
  const int len = lengths[bB];
  const int d0 = lane * 16;
  const int dt = tid & 63;
  const int d2c = slice*128 + dt*2;            // ctx/gates dim pair

  float va[16];
  #pragma unroll
  for (int q = 0; q < 4; ++q){
    float4 t4 = *(const float4*)(v_a + d0 + q*4);
    va[q*4+0] = t4.x; va[q*4+1] = t4.y; va[q*4+2] = t4.z; va[q*4+3] = t4.w;
  }
  u32 ep = 0;

  for (int t = 0; t < T_; ++t){
    // ===== Phase A: [hU|gh] cols [c0, c0+16) =====
    {
      bf16x8 af[8], bfr[8];
      #pragma unroll
      for (int i = 0; i < 8; ++i){
        int kk = wk*256 + i*32 + ((lane >> 4) << 3);
        af[i]  = ldh_sc(h_b16 + arow*D_ + kk);
        bfr[i] = *(const bf16x8*)(Bb + kk);
      }
      vwait0();
      f32x4 acc = {0.f, 0.f, 0.f, 0.f};
      #pragma unroll
      for (int i = 0; i < 8; ++i)
        acc = __builtin_amdgcn_mfma_f32_16x16x32_bf16(af[i], bfr[i], acc, 0, 0, 0);
      *(f32x4*)(shred + (w*64 + lane)*4) = acc;
    }
    __syncthreads();
    {
      int mt2 = tid >> 8, lq = tid & 255, lane2 = lq >> 2, q = lq & 3;
      float s = 0.f;
      #pragma unroll
      for (int wk2 = 0; wk2 < 4; ++wk2) s += shred[((wk2*2 + mt2)*64 + lane2)*4 + q];
      int m = mt2*16 + ((lane2 >> 4) << 2) + q;
      int nc = c0 + (lane2 & 15);
      if (nc < D_) st_sc(hU + m*D_ + nc, s);
      else         st_sc(gh + m*G3_ + (nc - D_), s + b_hh[nc - D_]);
    }
    grid_barrier(flags, gsense, ++ep, tid, blk);

    // ===== Phase BC =====
    // prefetch gate inputs (wave 0 only) — latency hides under scores
    f32x2 g0, g1, g2; float2 gsr, gsz, gsn, hv;
    if (tid < 64){
      const float* ghp = gh + bB*G3_;
      g0 = ld2_sc(ghp + d2c); g1 = ld2_sc(ghp + D_ + d2c); g2 = ld2_sc(ghp + 2*D_ + d2c);
      const float* gs = gx_sel + ((long)t*B_ + bB)*G3_;
      gsr = *(const float2*)(gs + d2c);
      gsz = *(const float2*)(gs + D_ + d2c);
      gsn = *(const float2*)(gs + 2*D_ + d2c);
      hv  = *(const float2*)(h_f32 + bB*D_ + d2c);
    }
    // hu: full hU[bB] row, 16 dims/lane (dup across waves)
    float hu[16];
    {
      const float* hup = hU + bB*D_ + d0;
      f32x4 a0 = ld4_sc(hup), a1 = ld4_sc(hup+4), a2 = ld4_sc(hup+8), a3 = ld4_sc(hup+12);
      vwait0();
      #pragma unroll
      for (int q = 0; q < 4; ++q){ hu[q] = a0[q]; hu[4+q] = a1[q]; hu[8+q] = a2[q]; hu[12+q] = a3[q]; }
    }
    // scores for all s (dup x8 blocks): wave w -> s = w*8..w*8+7
    #pragma unroll
    for (int i = 0; i < 8; ++i){
      int s = w*8 + i;
      if (s < len){
        const u16* epp = enc_proj + ((long)(bB*S_ + s))*D_ + d0;
        U8 e0, e1; e0.v = *(const bf16x8*)epp; e1.v = *(const bf16x8*)(epp + 8);
        float a = 0.f;
        #pragma unroll
        for (int e = 0; e < 8; ++e){
          a = fmaf(tanh_fast(bf2f(e0.u[e]) + hu[e]),     va[e],     a);
          a = fmaf(tanh_fast(bf2f(e1.u[e]) + hu[8 + e]), va[8 + e], a);
        }
        #pragma unroll
        for (int off = 32; off; off >>= 1) a += __shfl_xor(a, off);
        if (lane == 0) sc_lds[s] = a;
      }
    }
    __syncthreads();
    if (w == 0){
      int s = lane;
      float x = (s < len) ? sc_lds[s] : -1e30f;
      float m = x;
      #pragma unroll
      for (int off = 32; off; off >>= 1) m = fmaxf(m, __shfl_xor(m, off));
      float e = (s < len) ? __expf(x - m) : 0.f;
      float sum = e;
      #pragma unroll
      for (int off = 32; off; off >>= 1) sum += __shfl_xor(sum, off);
      wls[s] = e * __builtin_amdgcn_rcpf(sum);
    }
    __syncthreads();
    // ctx: thread (sgrp=w, dt): dims (d2c, d2c+1) of each gate; s-loop 8-way split
    {
      float ar0=0,ar1=0,az0=0,az1=0,an0=0,an1=0;
      const u16* basep = encW + (long)bB*S_*G3_ + d2c;
      #pragma unroll
      for (int j = 0; j < 8; ++j){
        int s = w + j*8;
        if (s < len){
          const u16* p = basep + (long)s*G3_;
          u32 rr = *(const u32*)p;
          u32 zz = *(const u32*)(p + D_);
          u32 nn = *(const u32*)(p + 2*D_);
          float wt = wls[s];
          ar0 = fmaf(wt, bf2f((u16)rr), ar0);  ar1 = fmaf(wt, bf2f((u16)(rr >> 16)), ar1);
          az0 = fmaf(wt, bf2f((u16)zz), az0);  az1 = fmaf(wt, bf2f((u16)(zz >> 16)), az1);
          an0 = fmaf(wt, bf2f((u16)nn), an0);  an1 = fmaf(wt, bf2f((u16)(nn >> 16)), an1);
        }
      }
      float* pp = shred + (w*64 + dt)*7;
      pp[0]=ar0; pp[1]=ar1; pp[2]=az0; pp[3]=az1; pp[4]=an0; pp[5]=an1;
    }
    __syncthreads();
    if (tid < 64){
      float ar0=0,ar1=0,az0=0,az1=0,an0=0,an1=0;
      #pragma unroll
      for (int g = 0; g < 8; ++g){
        const float* pp = shred + (g*64 + tid)*7;
        ar0 += pp[0]; ar1 += pp[1]; az0 += pp[2]; az1 += pp[3]; an0 += pp[4]; an1 += pp[5];
      }
      float r0 = sigmoid_fast(gsr.x + ar0 + g0[0]);
      float r1 = sigmoid_fast(gsr.y + ar1 + g0[1]);
      float z0 = sigmoid_fast(gsz.x + az0 + g1[0]);
      float z1 = sigmoid_fast(gsz.y + az1 + g1[1]);
      float n0 = tanh_fast(gsn.x + an0 + r0*g2[0]);
      float n1 = tanh_fast(gsn.y + an1 + r1*g2[1]);
      float hn0 = (1.f - z0)*n0 + z0*hv.x;
      float hn1 = (1.f - z1)*n1 + z1*hv.y;
      *(float2*)(h_f32 + bB*D_ + d2c) = make_float2(hn0, hn1);   // block-private
      u32 pack = ((u32)f2bf(hn1) << 16) | (u32)f2bf(hn0);
      stu_sc((u32*)(h_b16 + bB*D_ + d2c), pack);                 // coherent: read by all blocks
      long row = (long)t*B_ + bB;
      *(u32*)(H + row*D_ + d2c) = pack;                          // read after kernel end
    }
    grid_barrier(flags, gsense, ++ep, tid, blk);
  }
}

// ---------------- launch ----------------
extern "C" void kernel_launch(void* const* d_in, const int* in_sizes, int n_in,
                              void* d_out, int out_size, void* d_ws, size_t ws_size,
                              hipStream_t stream)
{
  const int*   tokens    = (const int*)  d_in[0];
  const float* hidden0   = (const float*)d_in[1];
  const float* enc       = (const float*)d_in[2];
  const int*   lengths   = (const int*)  d_in[3];
  // d_in[4] = teacher_forcing_ratio (1.0 -> teacher forcing always; greedy path dead)
  const float* embedding = (const float*)d_in[5];
  const float* Wa        = (const float*)d_in[6];
  const float* Ua        = (const float*)d_in[7];
  const float* v_a       = (const float*)d_in[8];
  const float* W_ih      = (const float*)d_in[9];
  const float* b_ih      = (const float*)d_in[10];
  const float* W_hh      = (const float*)d_in[11];
  const float* b_hh      = (const float*)d_in[12];
  const float* W_out     = (const float*)d_in[13];
  const float* b_out     = (const float*)d_in[14];
  float* out = (float*)d_out;
  char* ws = (char*)d_ws;

  u32*   flags    = (u32*)  (ws + OFF_FLAGS);
  u32*   gsense   = (u32*)  (ws + OFF_FLAGS + 2048);
  float* h_f32    = (float*)(ws + OFF_H32);
  u16*   h_b16    = (u16*)  (ws + OFF_HB);
  float* hU       = (float*)(ws + OFF_HU);
  float* gh       = (float*)(ws + OFF_GH);
  u16*   H        = (u16*)  (ws + OFF_HH);
  char*  scr      = ws + OFF_SCR;
  u16*   M1T      = (u16*)  (scr + SC_M1T);
  u16*   Wa_bt    = (u16*)  (scr + SC_WABT);
  u16*   enc_b    = (u16*)  (scr + SC_ENCB);
  u16*   eproj    = (u16*)  (scr + SC_EPROJ);
  u16*   Wsel     = (u16*)  (scr + SC_WSEL);
  u16*   Wctx     = (u16*)  (scr + SC_WCTX);
  u16*   encW     = (u16*)  (scr + SC_ENCW);
  u16*   teach    = (u16*)  (scr + SC_TEACH);
  float* gx_sel   = (float*)(scr + SC_GXSEL);
  u16*   W_out_b  = (u16*)  scr;   // overlay: scratch is dead after recurrence

  // init + weight conversion / precompute
  k_zero32<<<dim3(4), dim3(256), 0, stream>>>((u32*)(ws + OFF_FLAGS), 1024);  // flags + gsense region
  k_f2b<<<dim3(2048), dim3(256), 0, stream>>>(enc, enc_b, (long)(2048*1024/4));
  k_transpose_f2b<<<dim3(32,32), dim3(256), 0, stream>>>(Ua, M1T, 1024, 1024);       // M1T[n][k]=Ua[k][n]
  k_transpose_f2b<<<dim3(32,32), dim3(256), 0, stream>>>(Wa, Wa_bt, 1024, 1024);     // Wa_bt[d][e]=Wa[e][d]
  k_f2b<<<dim3(2048), dim3(256), 0, stream>>>(W_hh, M1T + 1024*1024, (long)(3072*1024/4));
  k_subcopy<<<dim3(2048), dim3(256), 0, stream>>>(W_ih, Wsel, 3072, 1536, 0, 512);
  k_subcopy<<<dim3(2048), dim3(256), 0, stream>>>(W_ih, Wctx, 3072, 1536, 512, 1024);
  k_teach<<<dim3(2016), dim3(128), 0, stream>>>(embedding, tokens, teach);
  k_h0<<<dim3(128), dim3(256), 0, stream>>>(hidden0, h_f32, h_b16);

  // precompute GEMMs (grid = (bm, bn): bm fast for B-tile L2/HBM reuse)
  k_gemm<0><<<dim3(16,8),  dim3(256), 0, stream>>>(enc_b, Wa_bt, nullptr, eproj, nullptr, 2048, 1024, 1024, 2048);
  k_gemm<0><<<dim3(16,24), dim3(256), 0, stream>>>(enc_b, Wctx,  nullptr, encW,  nullptr, 2048, 3072, 1024, 2048);
  k_gemm<1><<<dim3(16,24), dim3(256), 0, stream>>>(teach, Wsel,  gx_sel, nullptr, b_ih,  2048, 3072, 512,  2048);

  // 63-step recurrence (persistent, 256 co-resident blocks, r7 barriers — byte-identical)
  k_recur<<<dim3(NB_), dim3(512), 0, stream>>>(h_f32, h_b16, hU, gh, H,
                                               M1T, eproj, encW, gx_sel, v_a, b_hh, lengths,
                                               flags, gsense);

  // batched output projection (bm fast: W_out_b swept ~once from HBM)
  k_f2b<<<dim3(4096), dim3(256), 0, stream>>>(W_out, W_out_b, (long)(32000*1024/4));
  k_gemm<2><<<dim3(16,250), dim3(256), 0, stream>>>(H, W_out_b, out, nullptr, b_out, 2048, 32000, 1024, 2016);
  k_out0<<<dim3(1000), dim3(1024), 0, stream>>>(out);
}